// Round 8
// baseline (903.054 us; speedup 1.0000x reference)
//
#include <hip/hip_runtime.h>

// Problem constants
#define B_   4
#define L_   2048
#define DIN  1024
#define DOUT 1024
#define H_   16
#define DH_  64
#define M_   (B_ * L_)   // 8192 rows

typedef __bf16 bf16x8 __attribute__((ext_vector_type(8)));
typedef float  f32x4  __attribute__((ext_vector_type(4)));

__device__ __forceinline__ float bf2f(unsigned short u) {
  union { unsigned int i; float f; } x; x.i = ((unsigned int)u) << 16; return x.f;
}
__device__ __forceinline__ unsigned short f2bf(float f) {
  union { float f; unsigned int i; } x; x.f = f;
  unsigned int r = x.i + 0x7FFFu + ((x.i >> 16) & 1u);
  return (unsigned short)(r >> 16);
}

// DPP cross-lane add (VALU latency, no DS pipe). 0xB1=quad_perm[1,0,3,2],
// 0x4E=quad_perm[2,3,0,1], 0x124=row_ror:4, 0x128=row_ror:8 -> 16-lane allreduce.
template <int CTRL>
__device__ __forceinline__ float dpp_add(float x) {
  int v = __builtin_amdgcn_update_dpp(0, __float_as_int(x), CTRL, 0xF, 0xF, false);
  return x + __int_as_float(v);
}
__device__ __forceinline__ float row16_allreduce(float x) {
  x = dpp_add<0xB1>(x);
  x = dpp_add<0x4E>(x);
  x = dpp_add<0x124>(x);
  x = dpp_add<0x128>(x);
  return x;
}

// ---------------------------------------------------------------------------
// fp32 -> (hi, lo) bf16 split: hi = bf16(x), lo = bf16(x - hi).
// ---------------------------------------------------------------------------
__global__ __launch_bounds__(256)
void cast_hilo(const float* __restrict__ in,
               unsigned short* __restrict__ hi,
               unsigned short* __restrict__ lo, int n)
{
  int i = (blockIdx.x * 256 + threadIdx.x) * 8;
  int stride = gridDim.x * 256 * 8;
  for (; i < n; i += stride) {
    float4 a = *(const float4*)(in + i);
    float4 b = *(const float4*)(in + i + 4);
    float v[8] = {a.x, a.y, a.z, a.w, b.x, b.y, b.z, b.w};
    ushort4 h0, h1, l0, l1;
    unsigned short hh[8], ll[8];
#pragma unroll
    for (int j = 0; j < 8; j++) {
      hh[j] = f2bf(v[j]);
      ll[j] = f2bf(v[j] - bf2f(hh[j]));
    }
    h0 = {hh[0], hh[1], hh[2], hh[3]}; h1 = {hh[4], hh[5], hh[6], hh[7]};
    l0 = {ll[0], ll[1], ll[2], ll[3]}; l1 = {ll[4], ll[5], ll[6], ll[7]};
    *(ushort4*)(hi + i) = h0; *(ushort4*)(hi + i + 4) = h1;
    *(ushort4*)(lo + i) = l0; *(ushort4*)(lo + i + 4) = l1;
  }
}

// ---------------------------------------------------------------------------
// GEMM core: C[M,N] = A[M,K] @ W[N,K]^T (+bias), A/W as hi/lo bf16 pairs.
// acc = hi*hi + lo*hi + hi*lo (3 MFMAs). 128x128 tile, BK=64, 4 waves 2x2.
// LDS rows padded to 72 ushort (144 B): fragment reads 2-way max (free).
// ---------------------------------------------------------------------------
#define LPAD 72
template <typename OutT>
__device__ __forceinline__
void gemm_hilo_core(const unsigned short* __restrict__ Ahi,
                    const unsigned short* __restrict__ Alo,
                    const unsigned short* __restrict__ Whi,
                    const unsigned short* __restrict__ Wlo,
                    OutT* __restrict__ C,
                    const float* __restrict__ bias,
                    int K, int N, int m0, int n0)
{
  __shared__ unsigned short AsH[128][LPAD];
  __shared__ unsigned short AsL[128][LPAD];
  __shared__ unsigned short BsH[128][LPAD];
  __shared__ unsigned short BsL[128][LPAD];
  const int t = threadIdx.x;
  const int w = t >> 6;
  const int lane = t & 63;
  const int wm = (w >> 1) * 64, wn = (w & 1) * 64;
  const int l15 = lane & 15, quad = lane >> 4;

  f32x4 acc[4][4] = {};

  for (int k0 = 0; k0 < K; k0 += 64) {
#pragma unroll
    for (int i = 0; i < 4; i++) {
      int c = t + 256 * i;
      int row = c >> 3;
      int col = (c & 7) * 8;
      size_t ga = (size_t)(m0 + row) * K + k0 + col;
      size_t gb = (size_t)(n0 + row) * K + k0 + col;
      *(uint4*)(&AsH[row][col]) = *(const uint4*)(Ahi + ga);
      *(uint4*)(&AsL[row][col]) = *(const uint4*)(Alo + ga);
      *(uint4*)(&BsH[row][col]) = *(const uint4*)(Whi + gb);
      *(uint4*)(&BsL[row][col]) = *(const uint4*)(Wlo + gb);
    }
    __syncthreads();
#pragma unroll
    for (int kh = 0; kh < 2; kh++) {
      bf16x8 ah[4], al[4], bh[4], bl[4];
#pragma unroll
      for (int i = 0; i < 4; i++) {
        union U { uint4 u; bf16x8 v; } u0, u1, u2, u3;
        u0.u = *(const uint4*)(&AsH[wm + i * 16 + l15][kh * 32 + quad * 8]);
        u1.u = *(const uint4*)(&AsL[wm + i * 16 + l15][kh * 32 + quad * 8]);
        u2.u = *(const uint4*)(&BsH[wn + i * 16 + l15][kh * 32 + quad * 8]);
        u3.u = *(const uint4*)(&BsL[wn + i * 16 + l15][kh * 32 + quad * 8]);
        ah[i] = u0.v; al[i] = u1.v; bh[i] = u2.v; bl[i] = u3.v;
      }
#pragma unroll
      for (int mt = 0; mt < 4; mt++)
#pragma unroll
        for (int nt = 0; nt < 4; nt++) {
          acc[mt][nt] = __builtin_amdgcn_mfma_f32_16x16x32_bf16(ah[mt], bh[nt], acc[mt][nt], 0, 0, 0);
          acc[mt][nt] = __builtin_amdgcn_mfma_f32_16x16x32_bf16(al[mt], bh[nt], acc[mt][nt], 0, 0, 0);
          acc[mt][nt] = __builtin_amdgcn_mfma_f32_16x16x32_bf16(ah[mt], bl[nt], acc[mt][nt], 0, 0, 0);
        }
    }
    __syncthreads();
  }

#pragma unroll
  for (int mt = 0; mt < 4; mt++) {
#pragma unroll
    for (int nt = 0; nt < 4; nt++) {
      int n = n0 + wn + nt * 16 + l15;
      float bv = bias ? bias[n] : 0.0f;
#pragma unroll
      for (int r = 0; r < 4; r++) {
        int m = m0 + wm + mt * 16 + quad * 4 + r;
        C[(size_t)m * N + n] = (OutT)(acc[mt][nt][r] + bv);
      }
    }
  }
}

struct WPtrs {
  const unsigned short* hi[5];
  const unsigned short* lo[5];
};

__global__ __launch_bounds__(256, 2)
void proj_gemm(const unsigned short* __restrict__ xhi,
               const unsigned short* __restrict__ xlo,
               WPtrs wp, float* __restrict__ outbase)
{
  int z = blockIdx.z;
  float* C = outbase + (size_t)z * ((size_t)M_ * DOUT);
  gemm_hilo_core<float>(xhi, xlo, wp.hi[z], wp.lo[z], C, nullptr,
                        DIN, DOUT, blockIdx.x * 128, blockIdx.y * 128);
}

__global__ __launch_bounds__(256, 2)
void final_gemm(const unsigned short* __restrict__ chi,
                const unsigned short* __restrict__ clo,
                const unsigned short* __restrict__ whi,
                const unsigned short* __restrict__ wlo,
                float* __restrict__ out, const float* __restrict__ bias)
{
  gemm_hilo_core<float>(chi, clo, whi, wlo, out, bias,
                        DOUT, DOUT, blockIdx.x * 128, blockIdx.y * 128);
}

// ---------------------------------------------------------------------------
// alpha[r,h] = exp(-exp(A_log[h]) * softplus(x[r]·Wa[h] + dt_bias[h]))
// ---------------------------------------------------------------------------
__global__ __launch_bounds__(256)
void alpha_kernel(const float* __restrict__ x,
                  const float* __restrict__ Wa,
                  const float* __restrict__ dtb,
                  const float* __restrict__ Alg,
                  float* __restrict__ alpha)
{
  __shared__ float WaS[16 * 1024];
  const int t = threadIdx.x;
#pragma unroll
  for (int i = 0; i < 16; i++) {
    int idx = (t + 256 * i) * 4;
    *(float4*)(&WaS[idx]) = *(const float4*)(Wa + idx);
  }
  __syncthreads();
  const int w = t >> 6, lane = t & 63;
  for (int r = blockIdx.x * 4 + w; r < M_; r += gridDim.x * 4) {
    const float* xr = x + (size_t)r * DIN + lane * 16;
    float xv[16];
#pragma unroll
    for (int j = 0; j < 4; j++) {
      float4 a = *(const float4*)(xr + j * 4);
      xv[j * 4 + 0] = a.x; xv[j * 4 + 1] = a.y; xv[j * 4 + 2] = a.z; xv[j * 4 + 3] = a.w;
    }
#pragma unroll 1
    for (int h = 0; h < 16; h++) {
      const float* wr = &WaS[h * 1024 + lane * 16];
      float p = 0.f;
#pragma unroll
      for (int j = 0; j < 4; j++) {
        float4 b = *(const float4*)(wr + j * 4);
        p += xv[j * 4 + 0] * b.x + xv[j * 4 + 1] * b.y +
             xv[j * 4 + 2] * b.z + xv[j * 4 + 3] * b.w;
      }
#pragma unroll
      for (int o = 32; o >= 1; o >>= 1) p += __shfl_xor(p, o, 64);
      if (lane == h) {
        float z = p + dtb[h];
        float sp = (z > 20.f) ? z : log1pf(expf(z));
        alpha[(size_t)r * 16 + h] = expf(-expf(Alg[h]) * sp);
      }
    }
  }
}

// ---------------------------------------------------------------------------
// In-place fp32: q <- q/||q||/8, k <- k/||k||, beta <- sigmoid(beta_raw).
// ---------------------------------------------------------------------------
__global__ __launch_bounds__(256)
void qkb_kernel(float* __restrict__ q,
                float* __restrict__ k,
                float* __restrict__ bta)
{
  const int t = threadIdx.x, w = t >> 6, lane = t & 63;
  const int NP = M_ * H_;
  for (int p = blockIdx.x * 4 + w; p < NP; p += gridDim.x * 4) {
    size_t off = (size_t)p * 64 + lane;
    float qv = q[off];
    float kv = k[off];
    float bv = bta[off];
    float qs = qv * qv, ks = kv * kv;
#pragma unroll
    for (int o = 32; o >= 1; o >>= 1) {
      qs += __shfl_xor(qs, o, 64);
      ks += __shfl_xor(ks, o, 64);
    }
    q[off] = qv * rsqrtf(qs) * 0.125f;
    k[off] = kv * rsqrtf(ks);
    bta[off] = 1.0f / (1.0f + expf(-bv));
  }
}

// ---------------------------------------------------------------------------
// Scan v5: column-parallel + DPP reductions + LDS-staged windows.
// Block = (bh, part): 4 waves, 16 columns, all sharing the same k,q rows.
// Per 16-step window the whole block cooperatively stages k,q (16x64 f32
// each), v+beta (float2 per block-column), alpha into LDS (double-buffered,
// ~20 KB). Compute reads are ds_reads with compile-time immediate offsets
// (zero per-step address VALU); the 4 sub-groups' reads are same-address
// broadcasts (free). One barrier per window; stage loads get ~16 steps of
// compute as latency cover. Registers can't be forced to hold a burst
// (R7: compiler sank the window loads, VGPR=92) — LDS can.
// ---------------------------------------------------------------------------
#define SW 16
__global__ __launch_bounds__(256, 1)
void scan_kernel(const float* __restrict__ q,
                 const float* __restrict__ k,
                 const float* __restrict__ v,
                 const float* __restrict__ bta,
                 const float* __restrict__ alpha,
                 float* __restrict__ ys)
{
  __shared__ float4 kS[2][SW][16];
  __shared__ float4 qS[2][SW][16];
  __shared__ float2 vbS[2][SW][16];
  __shared__ float  aS[2][SW];

  const int bl = blockIdx.x;
  const int bh = bl & 63;                    // XCD-friendly: parts of bh share L2
  const int part = bl >> 6;                  // 0..3
  const int b = bh >> 4, h = bh & 15;
  const int t = threadIdx.x;
  const int w = t >> 6;
  const int lane = t & 63;
  const int sg = lane >> 4;                  // which column of the wave's 4
  const int i = lane & 15;                   // d-index: d = 4i..4i+3
  const int col = w * 4 + sg;                // block-local column 0..15
  const int e = part * 16 + col;             // global column 0..63

  const size_t rowstride = 1024;
  const size_t bhbase = (size_t)b * L_ * rowstride + (size_t)h * 64;
  const float* abase = alpha + (size_t)b * L_ * 16 + h;

  // staging roles (uniform per thread)
  const int s_rr = (t >> 4) & 15;            // k/q row within window
  const int s_cc = t & 15;                   // k/q float4 chunk
  const int s_tensor = t >> 8;               // unused (t<256); j-loop below
  (void)s_tensor;

  float4 S = {0.f, 0.f, 0.f, 0.f};
  float Yacc = 0.f;

#define STAGE(BUF, T0)                                                        \
  {                                                                           \
    _Pragma("unroll")                                                         \
    for (int j = 0; j < 2; j++) {                                             \
      /* idx 0..511: tensor = idx>>8, row = s_rr, chunk = s_cc */             \
      const float* src = (j ? q : k) + bhbase +                               \
                         (size_t)((T0) + s_rr) * rowstride + s_cc * 4;        \
      float4 val = *(const float4*)src;                                       \
      if (j) qS[BUF][s_rr][s_cc] = val; else kS[BUF][s_rr][s_cc] = val;       \
    }                                                                         \
    {                                                                         \
      size_t o = bhbase + (size_t)((T0) + s_rr) * rowstride + part * 16 + s_cc; \
      float2 vb2 = { v[o], bta[o] };                                          \
      vbS[BUF][s_rr][s_cc] = vb2;                                             \
    }                                                                         \
    if (t < SW) aS[BUF][t] = abase[(size_t)((T0) + t) * 16];                  \
  }

  STAGE(0, 0);
  __syncthreads();

  for (int w0 = 0; w0 < L_; w0 += SW) {
    const int buf = (w0 >> 4) & 1;
    if (w0 + SW < L_) { STAGE(buf ^ 1, w0 + SW); }
#pragma unroll
    for (int tt = 0; tt < SW; tt++) {
      float4 kc = kS[buf][tt][i];
      float4 qc = qS[buf][tt][i];
      float2 vb = vbS[buf][tt][col];
      float ac = aS[buf][tt];
      // kv = k · S_old (4 in-lane + 16-lane DPP allreduce)
      float p = kc.x * S.x + kc.y * S.y + kc.z * S.z + kc.w * S.w;
      p = row16_allreduce(p);
      float delta = (vb.x - ac * p) * vb.y;
      // S = a*S + k*delta
      S.x = fmaf(ac, S.x, kc.x * delta);
      S.y = fmaf(ac, S.y, kc.y * delta);
      S.z = fmaf(ac, S.z, kc.z * delta);
      S.w = fmaf(ac, S.w, kc.w * delta);
      // y = q · S
      float yp = qc.x * S.x + qc.y * S.y + qc.z * S.z + qc.w * S.w;
      yp = row16_allreduce(yp);
      if (i == tt) Yacc = yp;
    }
    ys[bhbase + (size_t)(w0 + i) * rowstride + e] = Yacc;
    __syncthreads();
  }
#undef STAGE
}

// ---------------------------------------------------------------------------
// ctx = rmsnorm(ys, norm_w) * silu(gate), written directly as hi/lo bf16.
// ---------------------------------------------------------------------------
__global__ __launch_bounds__(256)
void out_gate_kernel(const float* __restrict__ ys,
                     const float* __restrict__ g,
                     const float* __restrict__ norm_w,
                     unsigned short* __restrict__ chi,
                     unsigned short* __restrict__ clo)
{
  const int t = threadIdx.x, w = t >> 6, lane = t & 63;
  const int NP = M_ * H_;
  float nw = norm_w[lane];
  for (int p = blockIdx.x * 4 + w; p < NP; p += gridDim.x * 4) {
    size_t off = (size_t)p * 64 + lane;
    float y = ys[off];
    float gv = g[off];
    float s = y * y;
#pragma unroll
    for (int o = 32; o >= 1; o >>= 1) s += __shfl_xor(s, o, 64);
    float rs = rsqrtf(s * (1.0f / 64.0f) + 1e-6f);
    float silu = gv / (1.0f + expf(-gv));
    float c = y * rs * nw * silu;
    unsigned short hh = f2bf(c);
    chi[off] = hh;
    clo[off] = f2bf(c - bf2f(hh));
  }
}

// ---------------------------------------------------------------------------
extern "C" void kernel_launch(void* const* d_in, const int* in_sizes, int n_in,
                              void* d_out, int out_size, void* d_ws, size_t ws_size,
                              hipStream_t stream)
{
  const float* x   = (const float*)d_in[0];
  const float* Wq  = (const float*)d_in[1];
  const float* Wk  = (const float*)d_in[2];
  const float* Wv  = (const float*)d_in[3];
  const float* Wg  = (const float*)d_in[4];
  const float* Wb  = (const float*)d_in[5];
  const float* Wa  = (const float*)d_in[6];
  const float* dtb = (const float*)d_in[7];
  const float* Alg = (const float*)d_in[8];
  const float* nw  = (const float*)d_in[9];
  const float* Wo  = (const float*)d_in[10];
  const float* bo  = (const float*)d_in[11];

  const size_t TSZ = (size_t)M_ * DOUT;   // 8,388,608
  const size_t WSZ = (size_t)DOUT * DIN;  // 1,048,576

  float* q    = (float*)d_ws;             // projections q,k,v,g,bta contiguous
  float* k    = q + TSZ;
  float* v    = k + TSZ;
  float* g    = v + TSZ;
  float* bta  = g + TSZ;
  float* ys   = bta + TSZ;
  float* alph = ys + TSZ;                 // M_*H_ floats
  unsigned short* whl = (unsigned short*)(alph + (size_t)M_ * H_);
  unsigned short* whi[6], *wlo[6];
  for (int j = 0; j < 6; j++) { whi[j] = whl + (size_t)(2 * j) * WSZ; wlo[j] = whl + (size_t)(2 * j + 1) * WSZ; }
  // x hi/lo aliased into ys region (dead until scan)
  unsigned short* xhi = (unsigned short*)ys;
  unsigned short* xlo = xhi + TSZ;
  // ctx hi/lo aliased into q region (q dead after scan)
  unsigned short* chi = (unsigned short*)q;
  unsigned short* clo = chi + TSZ;
  float* outp = (float*)d_out;

  cast_hilo<<<2048, 256, 0, stream>>>(x, xhi, xlo, (int)TSZ);
  cast_hilo<<<512, 256, 0, stream>>>(Wq, whi[0], wlo[0], (int)WSZ);
  cast_hilo<<<512, 256, 0, stream>>>(Wk, whi[1], wlo[1], (int)WSZ);
  cast_hilo<<<512, 256, 0, stream>>>(Wv, whi[2], wlo[2], (int)WSZ);
  cast_hilo<<<512, 256, 0, stream>>>(Wg, whi[3], wlo[3], (int)WSZ);
  cast_hilo<<<512, 256, 0, stream>>>(Wb, whi[4], wlo[4], (int)WSZ);
  cast_hilo<<<512, 256, 0, stream>>>(Wo, whi[5], wlo[5], (int)WSZ);

  WPtrs wp;
  for (int j = 0; j < 5; j++) { wp.hi[j] = whi[j]; wp.lo[j] = wlo[j]; }
  dim3 gp(M_ / 128, DOUT / 128, 5);
  proj_gemm<<<gp, 256, 0, stream>>>(xhi, xlo, wp, q);

  alpha_kernel<<<128, 256, 0, stream>>>(x, Wa, dtb, Alg, alph);
  qkb_kernel<<<1024, 256, 0, stream>>>(q, k, bta);
  scan_kernel<<<256, 256, 0, stream>>>(q, k, v, bta, alph, ys);
  out_gate_kernel<<<1024, 256, 0, stream>>>(ys, g, nw, chi, clo);

  dim3 gf(M_ / 128, DOUT / 128);
  final_gemm<<<gf, 256, 0, stream>>>(chi, clo, whi[5], wlo[5], outp, bo);
}